// Round 3
// baseline (219.997 us; speedup 1.0000x reference)
//
#include <hip/hip_runtime.h>

#define NUM_USERS 100000
#define H1 256
#define H2 128
#define H3 64
#define BATCH 1024

// One block per batch row. All phases barrier-separated, pure fp32,
// no cross-lane intrinsics, every index statically in bounds.
__global__ __launch_bounds__(256) void mlp_row(
    const int* __restrict__ user_ids,
    const int* __restrict__ item_ids,
    const float* __restrict__ W1, const float* __restrict__ b1,
    const float* __restrict__ W2, const float* __restrict__ b2,
    const float* __restrict__ W3, const float* __restrict__ b3,
    const float* __restrict__ W4, const float* __restrict__ b4,
    float* __restrict__ out)
{
    __shared__ float h1[H1];
    __shared__ float h2[H2];
    __shared__ float h3[H3];
    __shared__ float res;

    const int t   = threadIdx.x;   // 0..255
    const int row = blockIdx.x;    // 0..1023

    const int u  = user_ids[row];  // wave-uniform
    const int it = item_ids[row];

    // ---- Layer 1: h1[t] = relu(W1[u][t] + W1[NU+it][t] + b1[t])
    {
        float v = W1[(size_t)u * H1 + t]
                + W1[(size_t)(NUM_USERS + it) * H1 + t]
                + b1[t];
        h1[t] = v > 0.f ? v : 0.f;
    }
    __syncthreads();

    // ---- Layer 2: h2[j] = relu(sum_k h1[k] * W2[k][j] + b2[j]), j = t < 128
    if (t < H2) {
        float acc = b2[t];
        for (int k = 0; k < H1; ++k)
            acc += h1[k] * W2[k * H2 + t];   // LDS broadcast * coalesced global
        h2[t] = acc > 0.f ? acc : 0.f;
    }
    __syncthreads();

    // ---- Layer 3: h3[j] = relu(sum_k h2[k] * W3[k][j] + b3[j]), j = t < 64
    if (t < H3) {
        float acc = b3[t];
        for (int k = 0; k < H2; ++k)
            acc += h2[k] * W3[k * H3 + t];
        h3[t] = acc > 0.f ? acc : 0.f;
    }
    __syncthreads();

    // ---- Layer 4: serial 64-dot by thread 0 (deterministic, ~trivial cost)
    if (t == 0) {
        float acc = b4[0];
        for (int k = 0; k < H3; ++k)
            acc += h3[k] * W4[k];
        res = acc;
    }
    __syncthreads();

    // ---- Redundant store: one full wave writes the identical value.
    if (t < 64)
        out[row] = res;
}

extern "C" void kernel_launch(void* const* d_in, const int* in_sizes, int n_in,
                              void* d_out, int out_size, void* d_ws, size_t ws_size,
                              hipStream_t stream) {
    const int*   user_ids = (const int*)d_in[0];
    const int*   item_ids = (const int*)d_in[1];
    const float* W1 = (const float*)d_in[2];
    const float* b1 = (const float*)d_in[3];
    const float* W2 = (const float*)d_in[4];
    const float* b2 = (const float*)d_in[5];
    const float* W3 = (const float*)d_in[6];
    const float* b3 = (const float*)d_in[7];
    const float* W4 = (const float*)d_in[8];
    const float* b4 = (const float*)d_in[9];
    float* out = (float*)d_out;

    dim3 grid(BATCH);   // one block per row
    dim3 block(256);

    // Launched TWICE on purpose (identical work every call; idempotent).
    // Insurance against anything clobbering d_out concurrently with the
    // first kernel's execution inside a graph replay: the second launch
    // rewrites every output element.
    mlp_row<<<grid, block, 0, stream>>>(user_ids, item_ids,
                                        W1, b1, W2, b2, W3, b3, W4, b4, out);
    mlp_row<<<grid, block, 0, stream>>>(user_ids, item_ids,
                                        W1, b1, W2, b2, W3, b3, W4, b4, out);
}

// Round 4
// 211.206 us; speedup vs baseline: 1.0416x; 1.0416x over previous
//
#include <hip/hip_runtime.h>

#define NUM_USERS 100000
#define H1 256
#define H2 128
#define H3 64
#define BATCH 1024

// One block per batch row. All phases barrier-separated, pure fp32,
// no cross-lane intrinsics, every index statically in bounds.
// Kernel identical to the passing R3 version; only the second
// insurance launch was removed (testing whether it was load-bearing).
__global__ __launch_bounds__(256) void mlp_row(
    const int* __restrict__ user_ids,
    const int* __restrict__ item_ids,
    const float* __restrict__ W1, const float* __restrict__ b1,
    const float* __restrict__ W2, const float* __restrict__ b2,
    const float* __restrict__ W3, const float* __restrict__ b3,
    const float* __restrict__ W4, const float* __restrict__ b4,
    float* __restrict__ out)
{
    __shared__ float h1[H1];
    __shared__ float h2[H2];
    __shared__ float h3[H3];
    __shared__ float res;

    const int t   = threadIdx.x;   // 0..255
    const int row = blockIdx.x;    // 0..1023

    const int u  = user_ids[row];  // wave-uniform
    const int it = item_ids[row];

    // ---- Layer 1: h1[t] = relu(W1[u][t] + W1[NU+it][t] + b1[t])
    {
        float v = W1[(size_t)u * H1 + t]
                + W1[(size_t)(NUM_USERS + it) * H1 + t]
                + b1[t];
        h1[t] = v > 0.f ? v : 0.f;
    }
    __syncthreads();

    // ---- Layer 2: h2[j] = relu(sum_k h1[k] * W2[k][j] + b2[j]), j = t < 128
    if (t < H2) {
        float acc = b2[t];
        for (int k = 0; k < H1; ++k)
            acc += h1[k] * W2[k * H2 + t];   // LDS broadcast * coalesced global
        h2[t] = acc > 0.f ? acc : 0.f;
    }
    __syncthreads();

    // ---- Layer 3: h3[j] = relu(sum_k h2[k] * W3[k][j] + b3[j]), j = t < 64
    if (t < H3) {
        float acc = b3[t];
        for (int k = 0; k < H2; ++k)
            acc += h2[k] * W3[k * H3 + t];
        h3[t] = acc > 0.f ? acc : 0.f;
    }
    __syncthreads();

    // ---- Layer 4: serial 64-dot by thread 0 (deterministic, ~trivial cost)
    if (t == 0) {
        float acc = b4[0];
        for (int k = 0; k < H3; ++k)
            acc += h3[k] * W4[k];
        res = acc;
    }
    __syncthreads();

    // ---- Redundant store: one full wave writes the identical value.
    if (t < 64)
        out[row] = res;
}

extern "C" void kernel_launch(void* const* d_in, const int* in_sizes, int n_in,
                              void* d_out, int out_size, void* d_ws, size_t ws_size,
                              hipStream_t stream) {
    const int*   user_ids = (const int*)d_in[0];
    const int*   item_ids = (const int*)d_in[1];
    const float* W1 = (const float*)d_in[2];
    const float* b1 = (const float*)d_in[3];
    const float* W2 = (const float*)d_in[4];
    const float* b2 = (const float*)d_in[5];
    const float* W3 = (const float*)d_in[6];
    const float* b3 = (const float*)d_in[7];
    const float* W4 = (const float*)d_in[8];
    const float* b4 = (const float*)d_in[9];
    float* out = (float*)d_out;

    dim3 grid(BATCH);   // one block per row
    dim3 block(256);
    mlp_row<<<grid, block, 0, stream>>>(user_ids, item_ids,
                                        W1, b1, W2, b2, W3, b3, W4, b4, out);
}